// Round 2
// baseline (352.741 us; speedup 1.0000x reference)
//
#include <hip/hip_runtime.h>
#include <stdint.h>

typedef unsigned short ushort_t;
typedef __attribute__((ext_vector_type(8))) short short8;
typedef __attribute__((ext_vector_type(4))) float f32x4;
typedef __attribute__((ext_vector_type(4))) uint32_t u32x4;
typedef __attribute__((ext_vector_type(2))) uint32_t u32x2;

#define B_SZ 8
#define T_SZ 512
#define D_SZ 1024
#define KSTEPS 16  // D / 64

__device__ __forceinline__ ushort_t f2bf(float f) {
  union { float f; uint32_t i; } c; c.f = f;
  uint32_t u = c.i;
  u += 0x7fffu + ((u >> 16) & 1u);  // RNE
  return (ushort_t)(u >> 16);
}

// pack two fp32 -> {bf16(a) | bf16(b)<<16}; gfx950 has v_cvt_pk_bf16_f32 (RNE)
__device__ __forceinline__ uint32_t pk_bf16(float a, float b) {
#if __has_builtin(__builtin_amdgcn_cvt_pk_bf16_f32)
  typedef __bf16 bf2_t __attribute__((ext_vector_type(2)));
  union { bf2_t v; uint32_t u; } c;
  c.v = __builtin_amdgcn_cvt_pk_bf16_f32(a, b);
  return c.u;
#else
  return (uint32_t)f2bf(a) | ((uint32_t)f2bf(b) << 16);
#endif
}

// 512 threads = 8 waves. Waves 0-3: expert slot 0; waves 4-7: expert slot 1.
// 128x128 output tile per block, BK=64. fp32 in -> bf16 LDS tiles -> MFMA fp32 acc.
// LDS union: staging (A 16KB + BT[2] 32KB) / fp32 combine buffer (64KB).
__global__ __launch_bounds__(512, 2)
void moe_gemm(const float* __restrict__ x, const float* __restrict__ w,
              const float* __restrict__ Wb, const float* __restrict__ bb,
              const int* __restrict__ idx, float* __restrict__ out)
{
  __shared__ union {
    struct { ushort_t A[8192]; ushort_t BT[2][8192]; } st;  // 48 KB
    float comb[128 * 128];                                  // 64 KB
  } sm;

  const int tid  = threadIdx.x;
  const int lane = tid & 63;
  const int wave = tid >> 6;
  const int grp  = wave >> 2;   // expert slot
  const int wl   = wave & 3;    // 2x2 wave grid

  const int bid = blockIdx.x;
  const int b   = bid >> 5;
  const int mt  = (bid >> 3) & 3;
  const int nt  = bid & 7;

  const int   e  = idx[b * 2 + grp];
  const float wk = w[b * 2 + grp];
  const float* Wg = Wb + (size_t)e * (D_SZ * (size_t)D_SZ);

  ushort_t* As = sm.st.A;
  ushort_t* BT = sm.st.BT[grp];

  // ---- W load/transpose assignment: 256 threads per expert group
  const int tl = tid & 255;
  const int kg = tl >> 4;            // 4 consecutive k-rows each
  const int ng = tl & 15;            // 8 n-cols each
  const float* Wrow = Wg + (size_t)(kg * 4) * D_SZ + (nt * 128 + ng * 8);

  // ---- A staging assignment (all 512 threads, 2 fragments of 8 k-elems)
  const int f0 = tid, f1 = 512 + tid;
  const int am0 = f0 >> 3, am1 = f1 >> 3;
  const int kb0 = f0 & 7,  kb1 = f1 & 7;
  const float* xr0 = x + (size_t)(b * T_SZ + mt * 128 + am0) * D_SZ + kb0 * 8;
  const float* xr1 = x + (size_t)(b * T_SZ + mt * 128 + am1) * D_SZ + kb1 * 8;
  ushort_t* ad0 = As + am0 * 64 + (kb0 ^ (am0 & 7)) * 8;   // XOR-swizzled k-blocks
  ushort_t* ad1 = As + am1 * 64 + (kb1 ^ (am1 & 7)) * 8;

  // ---- prologue: load step-0 A and W into registers (fp32)
  f32x4 wreg[8];  // 4 rows x 8 floats
  f32x4 areg[4];  // 2 frags x 8 floats
#pragma unroll
  for (int r = 0; r < 4; ++r) {
    wreg[r * 2 + 0] = *(const f32x4*)(Wrow + (size_t)r * D_SZ);
    wreg[r * 2 + 1] = *(const f32x4*)(Wrow + (size_t)r * D_SZ + 4);
  }
  areg[0] = *(const f32x4*)(xr0);
  areg[1] = *(const f32x4*)(xr0 + 4);
  areg[2] = *(const f32x4*)(xr1);
  areg[3] = *(const f32x4*)(xr1 + 4);

  f32x4 acc[4][4];
#pragma unroll
  for (int mi = 0; mi < 4; ++mi)
#pragma unroll
    for (int ni = 0; ni < 4; ++ni) acc[mi][ni] = (f32x4){0.f, 0.f, 0.f, 0.f};

  const int mb = (wl >> 1) * 64;
  const int nb = (wl & 1) * 64;
  const int fm = lane & 15;
  const int quad = lane >> 4;

  for (int step = 0; step < KSTEPS; ++step) {
    // ---- staging: convert registers -> bf16 LDS tiles
    {
      u32x4 av0 = { pk_bf16(areg[0][0], areg[0][1]), pk_bf16(areg[0][2], areg[0][3]),
                    pk_bf16(areg[1][0], areg[1][1]), pk_bf16(areg[1][2], areg[1][3]) };
      *(u32x4*)ad0 = av0;
      u32x4 av1 = { pk_bf16(areg[2][0], areg[2][1]), pk_bf16(areg[2][2], areg[2][3]),
                    pk_bf16(areg[3][0], areg[3][1]), pk_bf16(areg[3][2], areg[3][3]) };
      *(u32x4*)ad1 = av1;
#pragma unroll
      for (int j = 0; j < 8; ++j) {
        const int n = ng * 8 + j;
        const int s = (n ^ (n >> 3)) & 7;
        const int elem = n * 64 + (((kg >> 1) ^ s) << 3) + ((kg & 1) << 2);
        const int hi = j >> 2, lo = j & 3;
        u32x2 dv = { pk_bf16(wreg[0 + hi][lo], wreg[2 + hi][lo]),
                     pk_bf16(wreg[4 + hi][lo], wreg[6 + hi][lo]) };
        *(u32x2*)(BT + elem) = dv;
      }
    }
    __syncthreads();  // tiles visible

    // ---- prefetch next step's A and W (latency hides under MFMA phase)
    if (step + 1 < KSTEPS) {
      const float* p = Wrow + (size_t)(step + 1) * 64 * D_SZ;
#pragma unroll
      for (int r = 0; r < 4; ++r) {
        wreg[r * 2 + 0] = *(const f32x4*)(p + (size_t)r * D_SZ);
        wreg[r * 2 + 1] = *(const f32x4*)(p + (size_t)r * D_SZ + 4);
      }
      const int ko = (step + 1) * 64;
      areg[0] = *(const f32x4*)(xr0 + ko);
      areg[1] = *(const f32x4*)(xr0 + ko + 4);
      areg[2] = *(const f32x4*)(xr1 + ko);
      areg[3] = *(const f32x4*)(xr1 + ko + 4);
    }

    // ---- MFMA phase
#pragma unroll
    for (int h = 0; h < 2; ++h) {
      short8 af[4], bfr[4];
#pragma unroll
      for (int mi = 0; mi < 4; ++mi) {
        const int m = mb + mi * 16 + fm;
        const int kbs = (h * 4 + quad) ^ (m & 7);
        af[mi] = *(const short8*)(As + m * 64 + kbs * 8);
      }
#pragma unroll
      for (int ni = 0; ni < 4; ++ni) {
        const int n = nb + ni * 16 + fm;
        const int kbs = (h * 4 + quad) ^ ((n ^ (n >> 3)) & 7);
        bfr[ni] = *(const short8*)(BT + n * 64 + kbs * 8);
      }
#pragma unroll
      for (int mi = 0; mi < 4; ++mi)
#pragma unroll
        for (int ni = 0; ni < 4; ++ni)
          acc[mi][ni] = __builtin_amdgcn_mfma_f32_16x16x32_bf16(af[mi], bfr[ni],
                                                                acc[mi][ni], 0, 0, 0);
    }
    __syncthreads();  // MFMA reads done before next staging overwrite
  }

  // ---- epilogue: bias + relu + gate weight (fp32)
  float bias_v[4];
#pragma unroll
  for (int ni = 0; ni < 4; ++ni)
    bias_v[ni] = bb[e * D_SZ + nt * 128 + nb + ni * 16 + fm];

#pragma unroll
  for (int mi = 0; mi < 4; ++mi)
#pragma unroll
    for (int ni = 0; ni < 4; ++ni)
#pragma unroll
      for (int rg = 0; rg < 4; ++rg) {
        float v = acc[mi][ni][rg] + bias_v[ni];
        v = v > 0.f ? v : 0.f;
        acc[mi][ni][rg] = v * wk;
      }

  // ---- combine the two expert slots through fp32 LDS, then coalesced store
  float* comb = sm.comb;
  if (grp == 1) {
#pragma unroll
    for (int mi = 0; mi < 4; ++mi)
#pragma unroll
      for (int ni = 0; ni < 4; ++ni)
#pragma unroll
        for (int rg = 0; rg < 4; ++rg) {
          const int row = mb + mi * 16 + quad * 4 + rg;
          const int col = nb + ni * 16 + fm;
          comb[row * 128 + col] = acc[mi][ni][rg];
        }
  }
  __syncthreads();
  if (grp == 0) {
#pragma unroll
    for (int mi = 0; mi < 4; ++mi)
#pragma unroll
      for (int ni = 0; ni < 4; ++ni)
#pragma unroll
        for (int rg = 0; rg < 4; ++rg) {
          const int row = mb + mi * 16 + quad * 4 + rg;
          const int col = nb + ni * 16 + fm;
          comb[row * 128 + col] += acc[mi][ni][rg];
        }
  }
  __syncthreads();
#pragma unroll
  for (int r = 0; r < 8; ++r) {
    const int c   = r * 512 + tid;   // float4 index in tile
    const int row = c >> 5;
    const int c4  = c & 31;
    f32x4 v = *(const f32x4*)(comb + row * 128 + c4 * 4);
    *(f32x4*)(out + (size_t)(b * T_SZ + mt * 128 + row) * D_SZ + nt * 128 + c4 * 4) = v;
  }
}

extern "C" void kernel_launch(void* const* d_in, const int* in_sizes, int n_in,
                              void* d_out, int out_size, void* d_ws, size_t ws_size,
                              hipStream_t stream) {
  const float* x  = (const float*)d_in[0];
  const float* w  = (const float*)d_in[1];
  const float* Wb = (const float*)d_in[2];
  const float* bb = (const float*)d_in[3];
  const int*   idx = (const int*)d_in[4];
  float* out = (float*)d_out;
  (void)in_sizes; (void)n_in; (void)out_size; (void)d_ws; (void)ws_size;

  dim3 grid(B_SZ * 4 * 8);   // 256 blocks: b(8) x mtile(4) x ntile(8)
  dim3 block(512);
  hipLaunchKernelGGL(moe_gemm, grid, block, 0, stream, x, w, Wb, bb, idx, out);
}

// Round 3
// 347.712 us; speedup vs baseline: 1.0145x; 1.0145x over previous
//
#include <hip/hip_runtime.h>
#include <stdint.h>

typedef unsigned short ushort_t;
typedef __attribute__((ext_vector_type(8))) short short8;
typedef __attribute__((ext_vector_type(4))) float f32x4;
typedef __attribute__((ext_vector_type(4))) uint32_t u32x4;
typedef __attribute__((ext_vector_type(2))) uint32_t u32x2;

#define B_SZ 8
#define T_SZ 512
#define D_SZ 1024
#define MT 256      // M tile (rows of x per block)
#define NT 64       // N tile (output cols per block)
#define BK 64       // K per step
#define KSTEPS 16   // D / BK
#define CSTRIDE 68  // combine-buffer row stride (fp32) — breaks 4-way epilogue conflicts

__device__ __forceinline__ ushort_t f2bf(float f) {
  union { float f; uint32_t i; } c; c.f = f;
  uint32_t u = c.i;
  u += 0x7fffu + ((u >> 16) & 1u);  // RNE
  return (ushort_t)(u >> 16);
}

__device__ __forceinline__ uint32_t pk_bf16(float a, float b) {
#if __has_builtin(__builtin_amdgcn_cvt_pk_bf16_f32)
  typedef __bf16 bf2_t __attribute__((ext_vector_type(2)));
  union { bf2_t v; uint32_t u; } c;
  c.v = __builtin_amdgcn_cvt_pk_bf16_f32(a, b);
  return c.u;
#else
  return (uint32_t)f2bf(a) | ((uint32_t)f2bf(b) << 16);
#endif
}

// 512 threads = 8 waves. Waves 0-3: expert slot 0; waves 4-7: slot 1.
// Block tile: 256x64 output, BK=64/step, double-buffered LDS, 1 barrier/step.
// Grid: bid&7 = batch (XCD-affine: x[b] ~2.1MB stays L2-resident per XCD),
//       mt = (bid>>3)>>4 in {0,1}, nt = (bid>>3)&15.
__global__ __launch_bounds__(512, 2)
void moe_gemm(const float* __restrict__ x, const float* __restrict__ w,
              const float* __restrict__ Wb, const float* __restrict__ bb,
              const int* __restrict__ idx, float* __restrict__ out)
{
  __shared__ union {
    struct {
      ushort_t A[2][MT * BK];       // 2 x 32 KB, XOR-swizzled k-blocks
      ushort_t BT[2][2][NT * BK];   // 2 bufs x 2 experts x 8 KB, [n][k] swizzled
    } st;                           // 96 KB
    float comb[MT * CSTRIDE];       // 68 KB epilogue combine
  } sm;

  const int tid  = threadIdx.x;
  const int lane = tid & 63;
  const int wave = tid >> 6;
  const int grp  = wave >> 2;
  const int wl   = wave & 3;

  const int bid = blockIdx.x;
  const int b   = bid & 7;          // XCD-affine batch
  const int rr  = bid >> 3;
  const int mt  = rr >> 4;          // 0..1
  const int nt  = rr & 15;          // 0..15

  const int   e  = idx[b * 2 + grp];
  const float wk = w[b * 2 + grp];
  const float* Wg = Wb + (size_t)e * (D_SZ * (size_t)D_SZ);

  // ---- W staging: 256 threads/group; kg:16 groups of 4 k-rows, ng:16 groups of 4 cols
  const int tl = tid & 255;
  const int kg = tl >> 4;
  const int ng = tl & 15;
  const float* Wrow = Wg + (size_t)(kg * 4) * D_SZ + (nt * NT + ng * 4);

  // ---- A staging: 4 fragments of 8 k-elems per thread (2048 frags / 512 thr)
  const float* xr[4];
  int aoff[4];
#pragma unroll
  for (int i = 0; i < 4; ++i) {
    const int f  = tid + 512 * i;
    const int am = f >> 3;
    const int kb = f & 7;
    xr[i]   = x + (size_t)(b * T_SZ + mt * MT + am) * D_SZ + kb * 8;
    aoff[i] = am * BK + (kb ^ (am & 7)) * 8;   // XOR-swizzled k-block slot
  }

  // ---- prologue: step-0 loads (fp32 registers)
  f32x4 areg[8], wreg[4];
#pragma unroll
  for (int i = 0; i < 4; ++i) {
    areg[2 * i + 0] = *(const f32x4*)(xr[i]);
    areg[2 * i + 1] = *(const f32x4*)(xr[i] + 4);
  }
#pragma unroll
  for (int r = 0; r < 4; ++r)
    wreg[r] = *(const f32x4*)(Wrow + (size_t)r * D_SZ);

  f32x4 acc[4][4];
#pragma unroll
  for (int mi = 0; mi < 4; ++mi)
#pragma unroll
    for (int ni = 0; ni < 4; ++ni) acc[mi][ni] = (f32x4){0.f, 0.f, 0.f, 0.f};

  const int fm   = lane & 15;
  const int quad = lane >> 4;
  const int mb   = wl * 64;    // wave's 64-row strip; all waves span full NT=64

  for (int step = 0; step < KSTEPS; ++step) {
    const int buf = step & 1;
    ushort_t* As = sm.st.A[buf];
    ushort_t* Bt = sm.st.BT[buf][grp];

    // ---- stage: cvt fp32 regs -> bf16 LDS tiles
#pragma unroll
    for (int i = 0; i < 4; ++i) {
      u32x4 av = { pk_bf16(areg[2*i][0],   areg[2*i][1]),
                   pk_bf16(areg[2*i][2],   areg[2*i][3]),
                   pk_bf16(areg[2*i+1][0], areg[2*i+1][1]),
                   pk_bf16(areg[2*i+1][2], areg[2*i+1][3]) };
      *(u32x4*)(As + aoff[i]) = av;
    }
#pragma unroll
    for (int j = 0; j < 4; ++j) {
      const int n = ng * 4 + j;
      const int s = (n ^ (n >> 3)) & 7;
      const int elem = n * BK + (((kg >> 1) ^ s) << 3) + ((kg & 1) << 2);
      u32x2 dv = { pk_bf16(wreg[0][j], wreg[1][j]),
                   pk_bf16(wreg[2][j], wreg[3][j]) };
      *(u32x2*)(Bt + elem) = dv;
    }
    __syncthreads();   // single barrier: tiles visible; WAR safe via double buffer

    // ---- prefetch step+1 (hides under MFMA phase)
    if (step + 1 < KSTEPS) {
      const int ko = (step + 1) * BK;
#pragma unroll
      for (int i = 0; i < 4; ++i) {
        areg[2 * i + 0] = *(const f32x4*)(xr[i] + ko);
        areg[2 * i + 1] = *(const f32x4*)(xr[i] + ko + 4);
      }
      const float* p = Wrow + (size_t)ko * D_SZ;
#pragma unroll
      for (int r = 0; r < 4; ++r)
        wreg[r] = *(const f32x4*)(p + (size_t)r * D_SZ);
    }

    // ---- MFMA phase
#pragma unroll
    for (int h = 0; h < 2; ++h) {
      short8 af[4], bfr[4];
#pragma unroll
      for (int mi = 0; mi < 4; ++mi) {
        const int m = mb + mi * 16 + fm;
        const int kbs = (h * 4 + quad) ^ (m & 7);
        af[mi] = *(const short8*)(As + m * BK + kbs * 8);
      }
#pragma unroll
      for (int ni = 0; ni < 4; ++ni) {
        const int n = ni * 16 + fm;
        const int kbs = (h * 4 + quad) ^ ((n ^ (n >> 3)) & 7);
        bfr[ni] = *(const short8*)(Bt + n * BK + kbs * 8);
      }
#pragma unroll
      for (int mi = 0; mi < 4; ++mi)
#pragma unroll
        for (int ni = 0; ni < 4; ++ni)
          acc[mi][ni] = __builtin_amdgcn_mfma_f32_16x16x32_bf16(af[mi], bfr[ni],
                                                                acc[mi][ni], 0, 0, 0);
    }
  }

  // ---- epilogue: bias + relu + gate
  float bias_v[4];
#pragma unroll
  for (int ni = 0; ni < 4; ++ni)
    bias_v[ni] = bb[e * D_SZ + nt * NT + ni * 16 + fm];

#pragma unroll
  for (int mi = 0; mi < 4; ++mi)
#pragma unroll
    for (int ni = 0; ni < 4; ++ni)
#pragma unroll
      for (int rg = 0; rg < 4; ++rg) {
        float v = acc[mi][ni][rg] + bias_v[ni];
        v = v > 0.f ? v : 0.f;
        acc[mi][ni][rg] = v * wk;
      }

  // ---- combine expert slots via LDS (aliases staging buffers)
  __syncthreads();
  float* comb = sm.comb;
  if (grp == 1) {
#pragma unroll
    for (int mi = 0; mi < 4; ++mi)
#pragma unroll
      for (int ni = 0; ni < 4; ++ni)
#pragma unroll
        for (int rg = 0; rg < 4; ++rg) {
          const int row = mb + mi * 16 + quad * 4 + rg;
          const int col = ni * 16 + fm;
          comb[row * CSTRIDE + col] = acc[mi][ni][rg];
        }
  }
  __syncthreads();
  if (grp == 0) {
#pragma unroll
    for (int mi = 0; mi < 4; ++mi)
#pragma unroll
      for (int ni = 0; ni < 4; ++ni)
#pragma unroll
        for (int rg = 0; rg < 4; ++rg) {
          const int row = mb + mi * 16 + quad * 4 + rg;
          const int col = ni * 16 + fm;
          comb[row * CSTRIDE + col] += acc[mi][ni][rg];
        }
  }
  __syncthreads();

  // ---- coalesced fp32 store: 256x64 tile, 8 float4 per thread
#pragma unroll
  for (int r = 0; r < 8; ++r) {
    const int c   = r * 512 + tid;     // float4 index
    const int row = c >> 4;            // 16 float4 per row
    const int c4  = c & 15;
    f32x4 v = *(const f32x4*)(comb + row * CSTRIDE + c4 * 4);
    *(f32x4*)(out + (size_t)(b * T_SZ + mt * MT + row) * D_SZ + nt * NT + c4 * 4) = v;
  }
}

extern "C" void kernel_launch(void* const* d_in, const int* in_sizes, int n_in,
                              void* d_out, int out_size, void* d_ws, size_t ws_size,
                              hipStream_t stream) {
  const float* x  = (const float*)d_in[0];
  const float* w  = (const float*)d_in[1];
  const float* Wb = (const float*)d_in[2];
  const float* bb = (const float*)d_in[3];
  const int*   idx = (const int*)d_in[4];
  float* out = (float*)d_out;
  (void)in_sizes; (void)n_in; (void)out_size; (void)d_ws; (void)ws_size;

  dim3 grid(256);   // b(8, low bits -> XCD-affine) x mt(2) x nt(16)
  dim3 block(512);
  hipLaunchKernelGGL(moe_gemm, grid, block, 0, stream, x, w, Wb, bb, idx, out);
}